// Round 2
// baseline (627.793 us; speedup 1.0000x reference)
//
#include <hip/hip_runtime.h>
#include <float.h>

#define Nn 32
#define Ll 2048
#define Cc 128
#define SUP 64                  // timesteps per k_agg unit (supertile)
#define NSUP 32                 // Ll / SUP
#define FT 16                   // timesteps per k_apply unit (fine tile)
#define NFT 128                 // Ll / FT
#define OUTC 1172               // 3*384 + 20
#define NLC (Nn * Ll * Cc)      // 8388608
#define OUT_ELEMS ((size_t)Nn * Ll * OUTC)  // 76808192
#define NROWS (3 * Nn)          // 96 (inp, n) rows
#define AGGU (NROWS * NSUP)     // 3072 k_agg units
#define FINEU (NROWS * NFT)     // 12288 k_apply units

typedef float  f4 __attribute__((ext_vector_type(4)));
typedef int    i4 __attribute__((ext_vector_type(4)));

__device__ __forceinline__ void nts4(f4* p, f4 v) { __builtin_nontemporal_store(v, p); }
__device__ __forceinline__ void nts1(float* p, float v) { __builtin_nontemporal_store(v, p); }

// ---------------- Phase 1: supertile stream + fine-prefix snapshots + MLP ----------------
// Each 32-lane unit streams SUP=64 timesteps of one (inp, n) row (4 ch/lane).
// At every FT=16 boundary it snapshots the running (max, idx, sum) BEFORE the
// sub-tile -> exclusive fine-prefix within the supertile. At the end it writes
// the supertile aggregate. Last block runs the demographics MLP.
__global__ __launch_bounds__(256) void k_agg(
        const float* __restrict__ x0, const float* __restrict__ x1,
        const float* __restrict__ x2,
        f4* __restrict__ fMax, i4* __restrict__ fIdx, f4* __restrict__ fSum,
        f4* __restrict__ sMax, i4* __restrict__ sIdx, f4* __restrict__ sSum,
        const float* __restrict__ dem, const float* __restrict__ W1,
        const float* __restrict__ b1, const float* __restrict__ W2,
        const float* __restrict__ b2, float* __restrict__ dvals) {
    if (blockIdx.x == AGGU / 8) {
        int n = threadIdx.x;
        if (n >= Nn) return;
        float de[8], h[40];
#pragma unroll
        for (int k = 0; k < 8; ++k) de[k] = dem[n * 8 + k];
#pragma unroll
        for (int j = 0; j < 40; ++j) {
            float s = b1[j];
#pragma unroll
            for (int k = 0; k < 8; ++k) s += de[k] * W1[k * 40 + j];
            h[j] = fmaxf(s, 0.f);
        }
#pragma unroll
        for (int o = 0; o < 20; ++o) {
            float s = b2[o];
#pragma unroll
            for (int j = 0; j < 40; ++j) s += h[j] * W2[j * 20 + o];
            dvals[n * 20 + o] = fmaxf(s, 0.f);
        }
        return;
    }

    int unit = blockIdx.x * 8 + (threadIdx.x >> 5);   // (inp, n, sup)
    int lane = threadIdx.x & 31;                      // channels lane*4..lane*4+3
    int inp = unit >> 10;                             // AGGU per inp = 1024
    int rem = unit & 1023;
    int n = rem >> 5;
    int sup = rem & 31;
    const float* x = (inp == 0) ? x0 : ((inp == 1) ? x1 : x2);
    int t0 = sup * SUP;
    const f4* p = (const f4*)(x + ((size_t)n * Ll + t0) * Cc) + lane;

    f4 m = { -FLT_MAX, -FLT_MAX, -FLT_MAX, -FLT_MAX };
    i4 mi = { 0, 0, 0, 0 };
    f4 s = { 0.f, 0.f, 0.f, 0.f };
    // fine unit fu = row*NFT + sup*4 + k == unit*4 + k  (row = inp*Nn + n)
    int fbase = (unit * 4) * (Cc / 4) + lane;
    for (int k = 0; k < 4; ++k) {
        int fo = fbase + k * (Cc / 4);
        fMax[fo] = m; fIdx[fo] = mi; fSum[fo] = s;    // exclusive prefix snapshot
#pragma unroll
        for (int tl = 0; tl < FT; ++tl) {
            int ti = k * FT + tl;
            f4 v = p[(size_t)ti * (Cc / 4)];
            int t = t0 + ti;
#pragma unroll
            for (int j = 0; j < 4; ++j) {
                s[j] += v[j];
                if (v[j] > m[j]) { m[j] = v[j]; mi[j] = t; }   // strict >: earlier wins ties
            }
        }
    }
    int so = unit * (Cc / 4) + lane;
    sMax[so] = m; sIdx[so] = mi; sSum[so] = s;
}

// ---- Phase 2: per-fine-tile units; carry = merge <=31 supertile aggs + fine prefix ----
// 12288 units -> 1536 blocks -> ~6 waves/SIMD (vs 1.5 before): enough wave supply
// to keep the VMEM read+store queues full on this store-dominated streaming kernel.
__global__ __launch_bounds__(256) void k_apply(
        const float* __restrict__ x0, const float* __restrict__ x1,
        const float* __restrict__ x2,
        const f4* __restrict__ fMax, const i4* __restrict__ fIdx,
        const f4* __restrict__ fSum,
        const f4* __restrict__ sMax, const i4* __restrict__ sIdx,
        const f4* __restrict__ sSum,
        const float* __restrict__ dvals, float* __restrict__ out) {
    int u = blockIdx.x * 8 + (threadIdx.x >> 5);
    int lane = threadIdx.x & 31;
    int inp = u >> 12;                                // FINEU per inp = 4096
    int rem = u & 4095;
    int n = rem >> 7;
    int tile = rem & 127;
    int row = inp * Nn + n;
    int S = tile >> 2;                                // supertile index
    const float* x = (inp == 0) ? x0 : ((inp == 1) ? x1 : x2);
    int t0 = tile * FT;

    // carry-in: exclusive merge of preceding supertiles (time order, strict >)
    f4 m = { -FLT_MAX, -FLT_MAX, -FLT_MAX, -FLT_MAX };
    i4 mi = { 0, 0, 0, 0 };
    f4 s = { 0.f, 0.f, 0.f, 0.f };
    int sb = row * NSUP * (Cc / 4) + lane;
#pragma unroll 4
    for (int j = 0; j < S; ++j) {
        int o = sb + j * (Cc / 4);
        f4 am = sMax[o]; i4 ai = sIdx[o]; f4 as = sSum[o];
#pragma unroll
        for (int jj = 0; jj < 4; ++jj) {
            if (am[jj] > m[jj]) { m[jj] = am[jj]; mi[jj] = ai[jj]; }
            s[jj] += as[jj];
        }
    }
    {   // fine prefix within this supertile (covers later time than all supers above)
        int fo = u * (Cc / 4) + lane;
        f4 am = fMax[fo]; i4 ai = fIdx[fo]; f4 as = fSum[fo];
#pragma unroll
        for (int jj = 0; jj < 4; ++jj) {
            if (am[jj] > m[jj]) { m[jj] = am[jj]; mi[jj] = ai[jj]; }
            s[jj] += as[jj];
        }
    }

    // MLP columns for this n (only inp==0 units write them)
    float dv = 0.f;
    if (inp == 0 && lane < 20) dv = dvals[n * 20 + lane];

    const f4* p = (const f4*)(x + ((size_t)n * Ll + t0) * Cc) + lane;
    // out row layout: inp*384 + {0:pmax, 128:pavg, 256:psum}, then 1152..1171 = d
    f4* omax = (f4*)(out + (size_t)n * Ll * OUTC + (size_t)t0 * OUTC + inp * 384) + lane;
    f4* oind = (f4*)(out + OUT_ELEMS + (size_t)inp * NLC + ((size_t)n * Ll + t0) * Cc) + lane;
    f4* oact = (f4*)(out + OUT_ELEMS + 3 * (size_t)NLC + (size_t)inp * NLC + ((size_t)n * Ll + t0) * Cc) + lane;
    float* dout = out + (size_t)n * Ll * OUTC + (size_t)t0 * OUTC + 1152 + (lane < 20 ? lane : 0);

    const float invL = 1.0f / (float)Ll;
#pragma unroll 4
    for (int tl = 0; tl < FT; ++tl) {
        f4 v = p[(size_t)tl * (Cc / 4)];
        int t = t0 + tl;
        bool haspad = (t < Ll - 1);
        float rcnt = __builtin_amdgcn_rcpf((float)(t + 1));   // ~1 ulp, well within threshold
        f4 pmax, pidx, pavg, psum;
#pragma unroll
        for (int j = 0; j < 4; ++j) {
            s[j] += v[j];
            if (v[j] > m[j]) { m[j] = v[j]; mi[j] = t; }
            float cmax = m[j];
            pmax[j] = haspad ? fmaxf(cmax, 0.f) : cmax;
            pidx[j] = (float)((haspad && cmax < 0.f) ? (t - (Ll - 1)) : mi[j]);
            pavg[j] = s[j] * invL;
            psum[j] = s[j] * rcnt;
        }
        size_t ro = (size_t)tl * (OUTC / 4);
        nts4(&omax[ro],          pmax);
        nts4(&omax[ro + Cc / 4], pavg);   // +128 floats
        nts4(&omax[ro + Cc / 2], psum);   // +256 floats
        nts4(&oind[(size_t)tl * (Cc / 4)], pidx);
        nts4(&oact[(size_t)tl * (Cc / 4)], pmax);
        if (inp == 0 && lane < 20)
            nts1(&dout[(size_t)tl * OUTC], dv);   // coalesced 80 B row segment
    }
}

extern "C" void kernel_launch(void* const* d_in, const int* in_sizes, int n_in,
                              void* d_out, int out_size, void* d_ws, size_t ws_size,
                              hipStream_t stream) {
    const float* x0  = (const float*)d_in[0];
    const float* x1  = (const float*)d_in[1];
    const float* x2  = (const float*)d_in[2];
    const float* dem = (const float*)d_in[3];
    const float* W1  = (const float*)d_in[4];
    const float* b1  = (const float*)d_in[5];
    const float* W2  = (const float*)d_in[6];
    const float* b2  = (const float*)d_in[7];
    float* out = (float*)d_out;

    // workspace layout (bytes):
    //   fMax/fIdx/fSum : FINEU*Cc*4 = 6.29 MB each
    //   sMax/sIdx/sSum : AGGU*Cc*4  = 1.57 MB each
    //   dvals          : 2.5 KB          (total ~23.6 MB)
    char* ws = (char*)d_ws;
    size_t FB = (size_t)FINEU * Cc * 4;
    size_t SB = (size_t)AGGU * Cc * 4;
    float* fMax = (float*)ws;
    int*   fIdx = (int*)(ws + FB);
    float* fSum = (float*)(ws + 2 * FB);
    float* sMax = (float*)(ws + 3 * FB);
    int*   sIdx = (int*)(ws + 3 * FB + SB);
    float* sSum = (float*)(ws + 3 * FB + 2 * SB);
    float* dvals = (float*)(ws + 3 * FB + 3 * SB);

    k_agg<<<dim3(AGGU / 8 + 1), dim3(256), 0, stream>>>(x0, x1, x2,
        (f4*)fMax, (i4*)fIdx, (f4*)fSum, (f4*)sMax, (i4*)sIdx, (f4*)sSum,
        dem, W1, b1, W2, b2, dvals);
    k_apply<<<dim3(FINEU / 8), dim3(256), 0, stream>>>(x0, x1, x2,
        (const f4*)fMax, (const i4*)fIdx, (const f4*)fSum,
        (const f4*)sMax, (const i4*)sIdx, (const f4*)sSum, dvals, out);
}